// Round 8
// baseline (433.552 us; speedup 1.0000x reference)
//
#include <hip/hip_runtime.h>
#include <hip/hip_cooperative_groups.h>

namespace cg = cooperative_groups;

// Problem constants
#define Bc 8
#define Nc 2048
#define Dc 512
#define PH 512            // P*H
#define NN 4194304        // N*N
#define NT 136            // upper-tri 128x128 tiles: 16*17/2

#define BM 128
#define BN 128
#define BK 32             // reverted to the verified R6 core

typedef __attribute__((ext_vector_type(8))) short bf16x8;
typedef __attribute__((ext_vector_type(4))) float f32x4;

static __device__ __forceinline__ unsigned short f2b(float x) {
    union { float f; unsigned u; } v; v.f = x;
    unsigned r = v.u + 0x7fffu + ((v.u >> 16) & 1u);   // RNE to bf16
    return (unsigned short)(r >> 16);
}

static __device__ __forceinline__ float b2f(unsigned short x) {
    return __builtin_bit_cast(float, (unsigned)x << 16);
}

// packed f32x2 -> bf16x2 (RNE), gfx950 instruction; low half = first operand
static __device__ __forceinline__ unsigned pk2(float lo, float hi) {
    unsigned r;
    asm("v_cvt_pk_bf16_f32 %0, %1, %2" : "=v"(r) : "v"(lo), "v"(hi));
    return r;
}

// async global->LDS DMA, 16 bytes per lane; LDS dest = wave-uniform base + lane*16
static __device__ __forceinline__ void load16_lds(const unsigned short* g, unsigned short* l) {
    __builtin_amdgcn_global_load_lds(
        (const __attribute__((address_space(1))) void*)g,
        (__attribute__((address_space(3))) void*)l,
        16, 0, 0);
}

// ---------------------------------------------------------------------------
// GEMM1 (fused conversion): F = relu(bf16(ctx) @ bf16(W)^T) from fp32 inputs.
// Verbatim R6 (BK=32, reg-staged conversion). grid 512 1-D, XCD swizzle.
// ---------------------------------------------------------------------------
__global__ __launch_bounds__(256) void gemm1_fused(
    const float* __restrict__ ctx, const float* __restrict__ W,
    unsigned short* __restrict__ F) {
    __shared__ unsigned short As[BM * BK];
    __shared__ unsigned short Bs[BN * BK];
    const int tid = threadIdx.x;
    const int lane = tid & 63;
    const int wave = tid >> 6;
    const int wm = wave >> 1, wn = wave & 1;
    const int bid = blockIdx.x;
    const int row0 = ((bid & 7) + ((bid >> 5) << 3)) * BM;   // y = (bid&7)+8*(bid>>5)
    const int col0 = ((bid >> 3) & 3) * BN;                  // c = (bid>>3)&3

    f32x4 acc[4][4] = {};

    for (int k0 = 0; k0 < Dc; k0 += BK) {
        int4 aw[2], bw[2];
#pragma unroll
        for (int j = 0; j < 2; ++j) {
            int e = j * 256 + tid;
            int rr = e >> 2, cc = e & 3;
            const float4* ga = (const float4*)&ctx[(size_t)(row0 + rr) * Dc + k0 + cc * 8];
            const float4* gb = (const float4*)&W[(size_t)(col0 + rr) * Dc + k0 + cc * 8];
            float4 a0 = ga[0], a1 = ga[1];
            float4 b0 = gb[0], b1 = gb[1];
            aw[j].x = pk2(a0.x, a0.y); aw[j].y = pk2(a0.z, a0.w);
            aw[j].z = pk2(a1.x, a1.y); aw[j].w = pk2(a1.z, a1.w);
            bw[j].x = pk2(b0.x, b0.y); bw[j].y = pk2(b0.z, b0.w);
            bw[j].z = pk2(b1.x, b1.y); bw[j].w = pk2(b1.z, b1.w);
        }
#pragma unroll
        for (int j = 0; j < 2; ++j) {
            int e = j * 256 + tid;
            *(int4*)&As[e * 8] = aw[j];
            *(int4*)&Bs[e * 8] = bw[j];
        }
        __syncthreads();

        bf16x8 af[4], bfr[4];
#pragma unroll
        for (int i = 0; i < 4; ++i) {
            af[i]  = *(const bf16x8*)&As[(wm * 64 + i * 16 + (lane & 15)) * BK + (lane >> 4) * 8];
            bfr[i] = *(const bf16x8*)&Bs[(wn * 64 + i * 16 + (lane & 15)) * BK + (lane >> 4) * 8];
        }
#pragma unroll
        for (int mi = 0; mi < 4; ++mi)
#pragma unroll
            for (int ni = 0; ni < 4; ++ni)
                acc[mi][ni] = __builtin_amdgcn_mfma_f32_16x16x32_bf16(af[mi], bfr[ni], acc[mi][ni], 0, 0, 0);
        __syncthreads();
    }

#pragma unroll
    for (int mi = 0; mi < 4; ++mi) {
#pragma unroll
        for (int ni = 0; ni < 4; ++ni) {
            int col  = col0 + wn * 64 + ni * 16 + (lane & 15);
            int rowb = row0 + wm * 64 + mi * 16 + ((lane >> 4) << 2);
#pragma unroll
            for (int r = 0; r < 4; ++r) {
                float v = fmaxf(acc[mi][ni][r], 0.0f);
                F[(size_t)(rowb + r) * PH + col] = f2b(v);
            }
        }
    }
}

// ---------------------------------------------------------------------------
// FUSED pass 2+3 (cooperative, grid 1024 x 256, 4 blocks/CU by construction):
// Phase 1: dynamic tile fetch (8 per-batch counters, XCD-preferred stealing);
//          per tile: verified BK=32 tri-GEMM -> e=exp in regs -> rsum atomics.
//          If a block takes another tile, it stashes the previous e (bf16) to
//          Estash (same-block write/read -> same-XCD L2, coherence-safe).
// Phase 2: grid.sync()  (rsum complete; device-scope atomics + coop barrier)
// Phase 3: scatter own tiles: last from registers (R1-verified epilogue:
//          direct orientation + Ts-transpose mirror), earlier from Estash
//          (R6-verified scatter body). invr computed inline per tile.
// LDS union: phase1 {As 8K | Bs 8K} / phase3 {Ts 16.9K | invA .5K | invB .5K}
// ---------------------------------------------------------------------------
__global__ __launch_bounds__(256, 4) void gemm2_fused(
    const unsigned short* __restrict__ F, float* __restrict__ rsum,
    unsigned int* __restrict__ ctrs, unsigned short* __restrict__ Estash,
    const int* __restrict__ mask, float* __restrict__ out) {
    __shared__ __align__(16) char smem[17920];
    __shared__ int tshare, sshare;
    unsigned short* As = (unsigned short*)smem;
    unsigned short* Bs = (unsigned short*)(smem + 8192);
    float* Ts   = (float*)smem;
    float* invA = (float*)(smem + 16896);
    float* invB = (float*)(smem + 17408);

    const int tid = threadIdx.x;
    const int lane = tid & 63;
    const int wave = tid >> 6;
    const int wm = wave >> 1, wn = wave & 1;
    const int l15 = lane & 15, q = lane >> 4;
    const int pref = blockIdx.x & 7;       // preferred batch (XCD heuristic)

    f32x4 acc[4][4];
    int ownT[4], ownS[4];
    int nT = 0;

    // ---------------- phase 1 ----------------
    for (int iter = 0; iter < 4; ++iter) {
        // fetch a tile: drain preferred batch first, then steal
        int tb = -1, ti = 0;
#pragma unroll 1
        for (int d = 0; d < 8; ++d) {
            const int bb = (pref + d) & 7;
            __syncthreads();
            if (tid == 0) tshare = (int)atomicAdd(&ctrs[bb], 1u);
            __syncthreads();
            const int v = tshare;
            if (v < NT) { tb = bb; ti = v; break; }
        }
        if (tb < 0) break;                 // all batches exhausted (uniform)

        if (nT > 0) {                      // free acc: stash previous tile's e
            if (tid == 0) sshare = (int)atomicAdd(&ctrs[8], 1u);
            __syncthreads();
            const int slot = sshare;
            ownS[nT - 1] = slot;
            unsigned short* Et = Estash + (size_t)slot * 16384;
#pragma unroll
            for (int mi = 0; mi < 4; ++mi)
#pragma unroll
                for (int ni = 0; ni < 4; ++ni)
#pragma unroll
                    for (int r = 0; r < 4; ++r)
                        Et[(wm * 64 + mi * 16 + (q << 2) + r) * 128 + wn * 64 + ni * 16 + l15] =
                            f2b(acc[mi][ni][r]);
        }

        // decode tile
        int j = 0;
        while (((j + 1) * (j + 2) / 2) <= ti) ++j;
        const int i = ti - j * (j + 1) / 2;
        const int row0 = i * BM, col0 = j * BN;
        const bool offd = (i != j);
        const unsigned short* Fb = F + (size_t)tb * Nc * PH;

#pragma unroll
        for (int mi = 0; mi < 4; ++mi)
#pragma unroll
            for (int ni = 0; ni < 4; ++ni) {
                f32x4 z = {0.f, 0.f, 0.f, 0.f};
                acc[mi][ni] = z;
            }

        // verified BK=32 tri-GEMM core (R6)
        for (int k0 = 0; k0 < PH; k0 += BK) {
#pragma unroll
            for (int jj = 0; jj < 2; ++jj) {
                int e = jj * 256 + tid;
                int rr = e >> 2, cc = e & 3;
                load16_lds(&Fb[(size_t)(row0 + rr) * PH + k0 + cc * 8], &As[e * 8]);
                if (offd)
                    load16_lds(&Fb[(size_t)(col0 + rr) * PH + k0 + cc * 8], &Bs[e * 8]);
            }
            __syncthreads();

            bf16x8 af[4], bfr[4];
#pragma unroll
            for (int qq = 0; qq < 4; ++qq)
                af[qq] = *(const bf16x8*)&As[(wm * 64 + qq * 16 + l15) * BK + q * 8];
            if (offd) {
#pragma unroll
                for (int qq = 0; qq < 4; ++qq)
                    bfr[qq] = *(const bf16x8*)&Bs[(wn * 64 + qq * 16 + l15) * BK + q * 8];
            } else {
#pragma unroll
                for (int qq = 0; qq < 4; ++qq)
                    bfr[qq] = *(const bf16x8*)&As[(wn * 64 + qq * 16 + l15) * BK + q * 8];
            }
#pragma unroll
            for (int mi = 0; mi < 4; ++mi)
#pragma unroll
                for (int ni = 0; ni < 4; ++ni)
                    acc[mi][ni] = __builtin_amdgcn_mfma_f32_16x16x32_bf16(af[mi], bfr[ni], acc[mi][ni], 0, 0, 0);
            __syncthreads();
        }

        // e = exp(S/16-32) in place + rsum atomics (R6-verified)
        float csum[4] = {0.f, 0.f, 0.f, 0.f};
        float rsm[4][4];
#pragma unroll
        for (int mi = 0; mi < 4; ++mi)
#pragma unroll
            for (int r = 0; r < 4; ++r) rsm[mi][r] = 0.f;

#pragma unroll
        for (int mi = 0; mi < 4; ++mi) {
#pragma unroll
            for (int ni = 0; ni < 4; ++ni) {
#pragma unroll
                for (int r = 0; r < 4; ++r) {
                    float e = __expf(acc[mi][ni][r] * 0.0625f - 32.0f);
                    acc[mi][ni][r] = e;
                    csum[ni] += e;
                    rsm[mi][r] += e;
                }
            }
        }
#pragma unroll
        for (int ni = 0; ni < 4; ++ni) {
            float s = csum[ni];
            s += __shfl_xor(s, 16);
            s += __shfl_xor(s, 32);
            if ((lane >> 4) == 0)
                atomicAdd(&rsum[tb * Nc + col0 + wn * 64 + ni * 16 + lane], s);
        }
        if (offd) {
#pragma unroll
            for (int mi = 0; mi < 4; ++mi) {
#pragma unroll
                for (int r = 0; r < 4; ++r) {
                    float s = rsm[mi][r];
                    s += __shfl_xor(s, 1);
                    s += __shfl_xor(s, 2);
                    s += __shfl_xor(s, 4);
                    s += __shfl_xor(s, 8);
                    if ((lane & 15) == 0)
                        atomicAdd(&rsum[tb * Nc + row0 + wm * 64 + mi * 16 + ((lane >> 4) << 2) + r], s);
                }
            }
        }
        ownT[nT++] = (tb << 16) | ti;
    }

    // ---------------- phase 2 ----------------
    cg::this_grid().sync();

    // ---------------- phase 3 ----------------
    const int cl = tid >> 3, f0 = tid & 7;
    const int mc = tid >> 1, h  = tid & 1;

    for (int s = 0; s < nT; ++s) {
        const int tb = ownT[s] >> 16, ti = ownT[s] & 0xffff;
        int j = 0;
        while (((j + 1) * (j + 2) / 2) <= ti) ++j;
        const int i = ti - j * (j + 1) / 2;
        const int row0 = i * BM, col0 = j * BN;
        const float* rsb = rsum + tb * Nc;
        const int*   mb  = mask + tb * Nc;
        float* outb = out + (size_t)tb * NN;

        __syncthreads();                   // protect invA/invB/Ts reuse
        if (tid < 128) invA[tid]       = (float)mb[col0 + tid]       / rsb[col0 + tid];
        else           invB[tid - 128] = (float)mb[row0 + tid - 128] / rsb[row0 + tid - 128];
        __syncthreads();

        if (s == nT - 1) {
            // ---- from registers (R1-verified epilogue) ----
            float iv[4];
#pragma unroll
            for (int ni = 0; ni < 4; ++ni) iv[ni] = invA[wn * 64 + ni * 16 + l15];
#pragma unroll
            for (int mi = 0; mi < 4; ++mi) {
                int rowb = row0 + wm * 64 + mi * 16 + (q << 2);
                const int4 mr4 = *(const int4*)&mb[rowb];
                float mr[4] = {(float)mr4.x, (float)mr4.y, (float)mr4.z, (float)mr4.w};
#pragma unroll
                for (int ni = 0; ni < 4; ++ni) {
                    int col = col0 + wn * 64 + ni * 16 + l15;
#pragma unroll
                    for (int r = 0; r < 4; ++r)
                        outb[(size_t)(rowb + r) * Nc + col] = acc[mi][ni][r] * iv[ni] * mr[r];
                }
            }
            if (i != j) {
#pragma unroll
                for (int ci = 0; ci < 4; ++ci) {
                    __syncthreads();
                    if (wn == (ci >> 1)) {
#pragma unroll
                        for (int ni2 = 0; ni2 < 2; ++ni2) {
                            int ni = (ci & 1) * 2 + ni2;
#pragma unroll
                            for (int mi = 0; mi < 4; ++mi)
                                *(float4*)&Ts[(ni2 * 16 + l15) * 132 + wm * 64 + mi * 16 + (q << 2)] =
                                    *(float4*)&acc[mi][ni];
                        }
                    }
                    __syncthreads();
                    int nn = col0 + ci * 32 + cl;
                    float mrow = (float)mb[nn];
                    float* orow = &outb[(size_t)nn * Nc + row0];
#pragma unroll
                    for (int g = 0; g < 4; ++g) {
                        int f = f0 + g * 8;
                        float4 ev  = *(float4*)&Ts[cl * 132 + 4 * f];
                        float4 iv4 = *(const float4*)&invB[4 * f];
                        float4 o;
                        o.x = ev.x * iv4.x * mrow;
                        o.y = ev.y * iv4.y * mrow;
                        o.z = ev.z * iv4.z * mrow;
                        o.w = ev.w * iv4.w * mrow;
                        *(float4*)&orow[4 * f] = o;
                    }
                }
            }
        } else {
            // ---- from Estash (R6-verified scatter body) ----
            const unsigned short* Et = Estash + (size_t)ownS[s] * 16384;
            for (int ci = 0; ci < 4; ++ci) {
                if (ci) __syncthreads();
                const int r = ci * 32 + cl;
                const int n = row0 + r;
                const float mrow = (float)mb[n];
#pragma unroll
                for (int g = 0; g < 2; ++g) {
                    const int c0 = 64 * g + 8 * f0;
                    union { int4 iv; unsigned short hv[8]; } u;
                    u.iv = *(const int4*)&Et[r * 128 + c0];
                    float ev[8];
#pragma unroll
                    for (int k = 0; k < 8; ++k) ev[k] = b2f(u.hv[k]);
                    *(float4*)&Ts[cl * 132 + c0]     = *(float4*)&ev[0];
                    *(float4*)&Ts[cl * 132 + c0 + 4] = *(float4*)&ev[4];
                    float4 iv0 = *(const float4*)&invA[c0];
                    float4 iv1 = *(const float4*)&invA[c0 + 4];
                    float4 o0, o1;
                    o0.x = ev[0] * iv0.x * mrow;
                    o0.y = ev[1] * iv0.y * mrow;
                    o0.z = ev[2] * iv0.z * mrow;
                    o0.w = ev[3] * iv0.w * mrow;
                    o1.x = ev[4] * iv1.x * mrow;
                    o1.y = ev[5] * iv1.y * mrow;
                    o1.z = ev[6] * iv1.z * mrow;
                    o1.w = ev[7] * iv1.w * mrow;
                    *(float4*)&outb[(size_t)n * Nc + col0 + c0]     = o0;
                    *(float4*)&outb[(size_t)n * Nc + col0 + c0 + 4] = o1;
                }
                if (i == j) continue;
                __syncthreads();
                const int a = col0 + mc;
                const float mcol = (float)mb[a];
                const int lb0 = ci * 32 + 16 * h;
                const int nb0 = row0 + lb0;
#pragma unroll
                for (int u2 = 0; u2 < 4; ++u2) {
                    float4 iv = *(const float4*)&invB[lb0 + 4 * u2];
                    float4 o;
                    o.x = Ts[(16 * h + 4 * u2 + 0) * 132 + mc] * iv.x * mcol;
                    o.y = Ts[(16 * h + 4 * u2 + 1) * 132 + mc] * iv.y * mcol;
                    o.z = Ts[(16 * h + 4 * u2 + 2) * 132 + mc] * iv.z * mcol;
                    o.w = Ts[(16 * h + 4 * u2 + 3) * 132 + mc] * iv.w * mcol;
                    *(float4*)&outb[(size_t)a * Nc + nb0 + 4 * u2] = o;
                }
            }
        }
    }
}

// ---------------------------------------------------------------------------
// R6-verified non-cooperative pair (fallback if cooperative launch fails).
// ---------------------------------------------------------------------------
__global__ __launch_bounds__(256) void gemm2_store(
    const unsigned short* __restrict__ F, float* __restrict__ rsum,
    unsigned short* __restrict__ Ework) {
    __shared__ unsigned short As[BM * BK];
    __shared__ unsigned short Bs[BN * BK];
    const int tid = threadIdx.x;
    const int lane = tid & 63;
    const int wave = tid >> 6;
    const int wm = wave >> 1, wn = wave & 1;
    const int l15 = lane & 15, q = lane >> 4;
    const int b = blockIdx.x & 7;
    const int idx = blockIdx.x >> 3;

    int j = 0;
    while (((j + 1) * (j + 2) / 2) <= idx) ++j;
    int i = idx - j * (j + 1) / 2;
    const int row0 = i * BM;
    const int col0 = j * BN;
    const bool offd = (i != j);
    const unsigned short* Fb = F + (size_t)b * Nc * PH;

    f32x4 acc[4][4] = {};

    for (int k0 = 0; k0 < PH; k0 += BK) {
#pragma unroll
        for (int jj = 0; jj < 2; ++jj) {
            int e = jj * 256 + tid;
            int rr = e >> 2, cc = e & 3;
            load16_lds(&Fb[(size_t)(row0 + rr) * PH + k0 + cc * 8], &As[e * 8]);
            if (offd)
                load16_lds(&Fb[(size_t)(col0 + rr) * PH + k0 + cc * 8], &Bs[e * 8]);
        }
        __syncthreads();

        bf16x8 af[4], bfr[4];
#pragma unroll
        for (int qq = 0; qq < 4; ++qq)
            af[qq] = *(const bf16x8*)&As[(wm * 64 + qq * 16 + l15) * BK + q * 8];
        if (offd) {
#pragma unroll
            for (int qq = 0; qq < 4; ++qq)
                bfr[qq] = *(const bf16x8*)&Bs[(wn * 64 + qq * 16 + l15) * BK + q * 8];
        } else {
#pragma unroll
            for (int qq = 0; qq < 4; ++qq)
                bfr[qq] = *(const bf16x8*)&As[(wn * 64 + qq * 16 + l15) * BK + q * 8];
        }
#pragma unroll
        for (int mi = 0; mi < 4; ++mi)
#pragma unroll
            for (int ni = 0; ni < 4; ++ni)
                acc[mi][ni] = __builtin_amdgcn_mfma_f32_16x16x32_bf16(af[mi], bfr[ni], acc[mi][ni], 0, 0, 0);
        __syncthreads();
    }

    unsigned short* Et = Ework + (size_t)(b * NT + idx) * 16384;

    float csum[4] = {0.f, 0.f, 0.f, 0.f};
    float rsm[4][4];
#pragma unroll
    for (int mi = 0; mi < 4; ++mi)
#pragma unroll
        for (int r = 0; r < 4; ++r) rsm[mi][r] = 0.f;

#pragma unroll
    for (int mi = 0; mi < 4; ++mi) {
#pragma unroll
        for (int ni = 0; ni < 4; ++ni) {
#pragma unroll
            for (int r = 0; r < 4; ++r) {
                float e = __expf(acc[mi][ni][r] * 0.0625f - 32.0f);
                Et[(wm * 64 + mi * 16 + (q << 2) + r) * 128 + wn * 64 + ni * 16 + l15] = f2b(e);
                csum[ni] += e;
                rsm[mi][r] += e;
            }
        }
    }
#pragma unroll
    for (int ni = 0; ni < 4; ++ni) {
        float s = csum[ni];
        s += __shfl_xor(s, 16);
        s += __shfl_xor(s, 32);
        if ((lane >> 4) == 0)
            atomicAdd(&rsum[b * Nc + col0 + wn * 64 + ni * 16 + lane], s);
    }
    if (offd) {
#pragma unroll
        for (int mi = 0; mi < 4; ++mi) {
#pragma unroll
            for (int r = 0; r < 4; ++r) {
                float s = rsm[mi][r];
                s += __shfl_xor(s, 1);
                s += __shfl_xor(s, 2);
                s += __shfl_xor(s, 4);
                s += __shfl_xor(s, 8);
                if ((lane & 15) == 0)
                    atomicAdd(&rsum[b * Nc + row0 + wm * 64 + mi * 16 + ((lane >> 4) << 2) + r], s);
            }
        }
    }
}

__global__ __launch_bounds__(256) void scatter_out(
    const unsigned short* __restrict__ Ework, const float* __restrict__ rsum,
    const int* __restrict__ mask, float* __restrict__ out) {
    __shared__ float Ts[32 * 132];
    __shared__ float invA[128];
    __shared__ float invB[128];
    const int tid = threadIdx.x;
    const int b = blockIdx.x & 7;
    const int idx = blockIdx.x >> 3;

    int j = 0;
    while (((j + 1) * (j + 2) / 2) <= idx) ++j;
    int i = idx - j * (j + 1) / 2;
    const int row0 = i * BM;
    const int col0 = j * BN;

    const unsigned short* Et = Ework + (size_t)(b * NT + idx) * 16384;
    const float* rsb  = rsum + b * Nc;
    const int*   mb   = mask + b * Nc;
    float* outb = out + (size_t)b * NN;

    if (tid < 128)       invA[tid]       = (float)mb[col0 + tid]       / rsb[col0 + tid];
    else                 invB[tid - 128] = (float)mb[row0 + tid - 128] / rsb[row0 + tid - 128];
    __syncthreads();

    const int cl = tid >> 3, f0 = tid & 7;
    const int mc = tid >> 1, h  = tid & 1;

    for (int ci = 0; ci < 4; ++ci) {
        if (ci) __syncthreads();
        const int r = ci * 32 + cl;
        const int n = row0 + r;
        const float mrow = (float)mb[n];
#pragma unroll
        for (int g = 0; g < 2; ++g) {
            const int c0 = 64 * g + 8 * f0;
            union { int4 iv; unsigned short hv[8]; } u;
            u.iv = *(const int4*)&Et[r * 128 + c0];
            float ev[8];
#pragma unroll
            for (int k = 0; k < 8; ++k) ev[k] = b2f(u.hv[k]);
            *(float4*)&Ts[cl * 132 + c0]     = *(float4*)&ev[0];
            *(float4*)&Ts[cl * 132 + c0 + 4] = *(float4*)&ev[4];
            float4 iv0 = *(const float4*)&invA[c0];
            float4 iv1 = *(const float4*)&invA[c0 + 4];
            float4 o0, o1;
            o0.x = ev[0] * iv0.x * mrow;
            o0.y = ev[1] * iv0.y * mrow;
            o0.z = ev[2] * iv0.z * mrow;
            o0.w = ev[3] * iv0.w * mrow;
            o1.x = ev[4] * iv1.x * mrow;
            o1.y = ev[5] * iv1.y * mrow;
            o1.z = ev[6] * iv1.z * mrow;
            o1.w = ev[7] * iv1.w * mrow;
            *(float4*)&outb[(size_t)n * Nc + col0 + c0]     = o0;
            *(float4*)&outb[(size_t)n * Nc + col0 + c0 + 4] = o1;
        }
        if (i == j) continue;
        __syncthreads();
        const int a = col0 + mc;
        const float mcol = (float)mb[a];
        const int lb0 = ci * 32 + 16 * h;
        const int nb0 = row0 + lb0;
#pragma unroll
        for (int u = 0; u < 4; ++u) {
            float4 iv = *(const float4*)&invB[lb0 + 4 * u];
            float4 o;
            o.x = Ts[(16 * h + 4 * u + 0) * 132 + mc] * iv.x * mcol;
            o.y = Ts[(16 * h + 4 * u + 1) * 132 + mc] * iv.y * mcol;
            o.z = Ts[(16 * h + 4 * u + 2) * 132 + mc] * iv.z * mcol;
            o.w = Ts[(16 * h + 4 * u + 3) * 132 + mc] * iv.w * mcol;
            *(float4*)&outb[(size_t)a * Nc + nb0 + 4 * u] = o;
        }
    }
}

// ---------------------------------------------------------------------------
// FALLBACK (small workspace): original recompute path, verbatim.
// ---------------------------------------------------------------------------
__global__ __launch_bounds__(256) void prep_kernel(
    const float* __restrict__ ctx, const float* __restrict__ W,
    unsigned short* __restrict__ Xb, unsigned short* __restrict__ Wb,
    float* __restrict__ rsum) {
    int t = blockIdx.x * 256 + threadIdx.x;
    if (t < 2097152) {
        float4 v = ((const float4*)ctx)[t];
        ushort4 o;
        o.x = f2b(v.x); o.y = f2b(v.y); o.z = f2b(v.z); o.w = f2b(v.w);
        ((ushort4*)Xb)[t] = o;
    }
    if (t < 65536) {
        float4 v = ((const float4*)W)[t];
        ushort4 o;
        o.x = f2b(v.x); o.y = f2b(v.y); o.z = f2b(v.z); o.w = f2b(v.w);
        ((ushort4*)Wb)[t] = o;
    }
    if (t < 4096) {
        float4 z; z.x = 0.f; z.y = 0.f; z.z = 0.f; z.w = 0.f;
        ((float4*)rsum)[t] = z;
    }
}

__global__ __launch_bounds__(256) void invr_kernel(
    const float* __restrict__ rsum, const int* __restrict__ mask,
    float* __restrict__ invr) {
    int t = blockIdx.x * 256 + threadIdx.x;
    if (t < Bc * Nc) invr[t] = (float)mask[t] / rsum[t];
}

__global__ __launch_bounds__(256) void gemm1_relu_fb(
    const unsigned short* __restrict__ Xb, const unsigned short* __restrict__ Wb,
    unsigned short* __restrict__ F) {
    __shared__ unsigned short As[BM * BK];
    __shared__ unsigned short Bs[BN * BK];
    const int tid = threadIdx.x;
    const int lane = tid & 63;
    const int wave = tid >> 6;
    const int wm = wave >> 1, wn = wave & 1;
    const int row0 = blockIdx.y * BM;
    const int col0 = blockIdx.x * BN;

    f32x4 acc[4][4] = {};

    for (int k0 = 0; k0 < Dc; k0 += BK) {
#pragma unroll
        for (int j = 0; j < 2; ++j) {
            int e = j * 256 + tid;
            int rr = e >> 2, cc = e & 3;
            load16_lds(&Xb[(size_t)(row0 + rr) * Dc + k0 + cc * 8], &As[e * 8]);
            load16_lds(&Wb[(size_t)(col0 + rr) * Dc + k0 + cc * 8], &Bs[e * 8]);
        }
        __syncthreads();

        bf16x8 af[4], bfr[4];
#pragma unroll
        for (int i = 0; i < 4; ++i) {
            af[i]  = *(const bf16x8*)&As[(wm * 64 + i * 16 + (lane & 15)) * BK + (lane >> 4) * 8];
            bfr[i] = *(const bf16x8*)&Bs[(wn * 64 + i * 16 + (lane & 15)) * BK + (lane >> 4) * 8];
        }
#pragma unroll
        for (int mi = 0; mi < 4; ++mi)
#pragma unroll
            for (int ni = 0; ni < 4; ++ni)
                acc[mi][ni] = __builtin_amdgcn_mfma_f32_16x16x32_bf16(af[mi], bfr[ni], acc[mi][ni], 0, 0, 0);
        __syncthreads();
    }

#pragma unroll
    for (int mi = 0; mi < 4; ++mi) {
#pragma unroll
        for (int ni = 0; ni < 4; ++ni) {
            int col  = col0 + wn * 64 + ni * 16 + (lane & 15);
            int rowb = row0 + wm * 64 + mi * 16 + ((lane >> 4) << 2);
#pragma unroll
            for (int r = 0; r < 4; ++r) {
                float v = fmaxf(acc[mi][ni][r], 0.0f);
                F[(size_t)(rowb + r) * PH + col] = f2b(v);
            }
        }
    }
}

__global__ __launch_bounds__(256) void gemm2_rsum(
    const unsigned short* __restrict__ F, float* __restrict__ rsum) {
    __shared__ unsigned short As[BM * BK];
    __shared__ unsigned short Bs[BN * BK];
    const int tid = threadIdx.x;
    const int lane = tid & 63;
    const int wave = tid >> 6;
    const int wm = wave >> 1, wn = wave & 1;
    const int b = blockIdx.y;

    int idx = blockIdx.x;
    int j = 0;
    while (((j + 1) * (j + 2) / 2) <= idx) ++j;
    int i = idx - j * (j + 1) / 2;
    const int row0 = i * BM;
    const int col0 = j * BN;
    const unsigned short* Fb = F + (size_t)b * Nc * PH;

    f32x4 acc[4][4] = {};

    for (int k0 = 0; k0 < PH; k0 += BK) {
#pragma unroll
        for (int jj = 0; jj < 2; ++jj) {
            int e = jj * 256 + tid;
            int rr = e >> 2, cc = e & 3;
            load16_lds(&Fb[(size_t)(row0 + rr) * PH + k0 + cc * 8], &As[e * 8]);
            load16_lds(&Fb[(size_t)(col0 + rr) * PH + k0 + cc * 8], &Bs[e * 8]);
        }
        __syncthreads();

        bf16x8 af[4], bfr[4];
#pragma unroll
        for (int q = 0; q < 4; ++q) {
            af[q]  = *(const bf16x8*)&As[(wm * 64 + q * 16 + (lane & 15)) * BK + (lane >> 4) * 8];
            bfr[q] = *(const bf16x8*)&Bs[(wn * 64 + q * 16 + (lane & 15)) * BK + (lane >> 4) * 8];
        }
#pragma unroll
        for (int mi = 0; mi < 4; ++mi)
#pragma unroll
            for (int ni = 0; ni < 4; ++ni)
                acc[mi][ni] = __builtin_amdgcn_mfma_f32_16x16x32_bf16(af[mi], bfr[ni], acc[mi][ni], 0, 0, 0);
        __syncthreads();
    }

    float csum[4] = {0.f, 0.f, 0.f, 0.f};
    float rsm[4][4];
#pragma unroll
    for (int mi = 0; mi < 4; ++mi)
#pragma unroll
        for (int r = 0; r < 4; ++r) rsm[mi][r] = 0.f;

#pragma unroll
    for (int mi = 0; mi < 4; ++mi) {
#pragma unroll
        for (int ni = 0; ni < 4; ++ni) {
#pragma unroll
            for (int r = 0; r < 4; ++r) {
                float e = __expf(acc[mi][ni][r] * 0.0625f - 32.0f);
                csum[ni] += e;
                rsm[mi][r] += e;
            }
        }
    }
#pragma unroll
    for (int ni = 0; ni < 4; ++ni) {
        float s = csum[ni];
        s += __shfl_xor(s, 16);
        s += __shfl_xor(s, 32);
        if ((lane >> 4) == 0)
            atomicAdd(&rsum[b * Nc + col0 + wn * 64 + ni * 16 + lane], s);
    }
    if (i != j) {
#pragma unroll
        for (int mi = 0; mi < 4; ++mi) {
#pragma unroll
            for (int r = 0; r < 4; ++r) {
                float s = rsm[mi][r];
                s += __shfl_xor(s, 1);
                s += __shfl_xor(s, 2);
                s += __shfl_xor(s, 4);
                s += __shfl_xor(s, 8);
                if ((lane & 15) == 0)
                    atomicAdd(&rsum[b * Nc + row0 + wm * 64 + mi * 16 + ((lane >> 4) << 2) + r], s);
            }
        }
    }
}

__global__ __launch_bounds__(256) void gemm2_write_sym(
    const unsigned short* __restrict__ F, const float* __restrict__ invr,
    const int* __restrict__ mask, float* __restrict__ out) {
    __shared__ unsigned short As[BM * BK];
    __shared__ unsigned short Bs[BN * BK];
    __shared__ float Ts[32 * 132];
    const int tid = threadIdx.x;
    const int lane = tid & 63;
    const int wave = tid >> 6;
    const int wm = wave >> 1, wn = wave & 1;
    const int l15 = lane & 15, q = lane >> 4;
    const int b = blockIdx.y;

    int idx = blockIdx.x;
    int j = 0;
    while (((j + 1) * (j + 2) / 2) <= idx) ++j;
    int i = idx - j * (j + 1) / 2;
    const int row0 = i * BM;
    const int col0 = j * BN;
    const unsigned short* Fb = F + (size_t)b * Nc * PH;

    f32x4 acc[4][4] = {};

    for (int k0 = 0; k0 < PH; k0 += BK) {
#pragma unroll
        for (int jj = 0; jj < 2; ++jj) {
            int e = jj * 256 + tid;
            int rr = e >> 2, cc = e & 3;
            load16_lds(&Fb[(size_t)(row0 + rr) * PH + k0 + cc * 8], &As[e * 8]);
            load16_lds(&Fb[(size_t)(col0 + rr) * PH + k0 + cc * 8], &Bs[e * 8]);
        }
        __syncthreads();

        bf16x8 af[4], bfr[4];
#pragma unroll
        for (int qq = 0; qq < 4; ++qq) {
            af[qq]  = *(const bf16x8*)&As[(wm * 64 + qq * 16 + l15) * BK + q * 8];
            bfr[qq] = *(const bf16x8*)&Bs[(wn * 64 + qq * 16 + l15) * BK + q * 8];
        }
#pragma unroll
        for (int mi = 0; mi < 4; ++mi)
#pragma unroll
            for (int ni = 0; ni < 4; ++ni)
                acc[mi][ni] = __builtin_amdgcn_mfma_f32_16x16x32_bf16(af[mi], bfr[ni], acc[mi][ni], 0, 0, 0);
        __syncthreads();
    }

#pragma unroll
    for (int mi = 0; mi < 4; ++mi)
#pragma unroll
        for (int ni = 0; ni < 4; ++ni)
#pragma unroll
            for (int r = 0; r < 4; ++r)
                acc[mi][ni][r] = __expf(acc[mi][ni][r] * 0.0625f - 32.0f);

    float* outb = out + (size_t)b * NN;

    float iv[4];
#pragma unroll
    for (int ni = 0; ni < 4; ++ni)
        iv[ni] = invr[b * Nc + col0 + wn * 64 + ni * 16 + l15];
#pragma unroll
    for (int mi = 0; mi < 4; ++mi) {
        int rowb = row0 + wm * 64 + mi * 16 + (q << 2);
        const int4 mr4 = *(const int4*)&mask[b * Nc + rowb];
        float mr[4] = {(float)mr4.x, (float)mr4.y, (float)mr4.z, (float)mr4.w};
#pragma unroll
        for (int ni = 0; ni < 4; ++ni) {
            int col = col0 + wn * 64 + ni * 16 + l15;
#pragma unroll
            for (int r = 0; r < 4; ++r)
                outb[(size_t)(rowb + r) * Nc + col] = acc[mi][ni][r] * iv[ni] * mr[r];
        }
    }

    if (i != j) {
#pragma unroll
        for (int ci = 0; ci < 4; ++ci) {
            __syncthreads();
            if (wn == (ci >> 1)) {
#pragma unroll
                for (int ni2 = 0; ni2 < 2; ++ni2) {
                    int ni = (ci & 1) * 2 + ni2;
#pragma unroll
                    for (int mi = 0; mi < 4; ++mi) {
                        *(float4*)&Ts[(ni2 * 16 + l15) * 132 + wm * 64 + mi * 16 + (q << 2)] =
                            *(float4*)&acc[mi][ni];
                    }
                }
            }
            __syncthreads();
            int cl = tid >> 3;
            int f0 = tid & 7;
            int nn = col0 + ci * 32 + cl;
            float mrow = (float)mask[b * Nc + nn];
            float* orow = &outb[(size_t)nn * Nc + row0];
#pragma unroll
            for (int g = 0; g < 4; ++g) {
                int f = f0 + g * 8;
                float4 ev  = *(float4*)&Ts[cl * 132 + 4 * f];
                float4 iv4 = *(const float4*)&invr[b * Nc + row0 + 4 * f];
                float4 o;
                o.x = ev.x * iv4.x * mrow;
                o.y = ev.y * iv4.y * mrow;
                o.z = ev.z * iv4.z * mrow;
                o.w = ev.w * iv4.w * mrow;
                *(float4*)&orow[4 * f] = o;
            }
        }
    }
}

// ---------------------------------------------------------------------------
extern "C" void kernel_launch(void* const* d_in, const int* in_sizes, int n_in,
                              void* d_out, int out_size, void* d_ws, size_t ws_size,
                              hipStream_t stream) {
    const float* ctx  = (const float*)d_in[0];   // [8,2048,512] fp32
    const float* W    = (const float*)d_in[1];   // [16,32,512] fp32
    const int*   mask = (const int*)d_in[2];     // [8,2048] int32
    float* out = (float*)d_out;                  // [8,2048,2048] fp32

    char* ws = (char*)d_ws;

    // Layout:
    //   [0 .. 35651584)           Estash (bf16, 1088 tile slots x 32KB)
    //   [35651584 .. 52428800)    F (bf16, 16384x512)
    //   [52428800 .. 52494336)    rsum (zeroed)
    //   [52494336 .. 52494400)    ctrs (9 uints used: 8 batch tile ctrs + stash)
    const size_t NEED = 52494400;

    if (ws_size >= NEED) {
        unsigned short* Estash = (unsigned short*)ws;
        unsigned short* F      = (unsigned short*)(ws + 35651584);
        float*          rsum   = (float*)(ws + 52428800);
        unsigned int*   ctrs   = (unsigned int*)(ws + 52494336);

        hipMemsetAsync(rsum, 0, 65536 + 64, stream);   // rsum + counters
        gemm1_fused<<<512, 256, 0, stream>>>(ctx, W, F);

        void* kargs[] = {(void*)&F, (void*)&rsum, (void*)&ctrs,
                         (void*)&Estash, (void*)&mask, (void*)&out};
        hipError_t cerr = hipLaunchCooperativeKernel(
            reinterpret_cast<const void*>(&gemm2_fused),
            dim3(1024), dim3(256), kargs, 0, stream);
        if (cerr != hipSuccess) {
            (void)hipGetLastError();   // clear; run verified non-coop pair
            gemm2_store<<<1088, 256, 0, stream>>>(F, rsum, Estash);
            scatter_out<<<1088, 256, 0, stream>>>(Estash, rsum, mask, out);
        }
    } else {
        // fallback: original recompute path (needs ~34.2 MB)
        unsigned short* Xb = (unsigned short*)ws;
        unsigned short* Wb = (unsigned short*)(ws + 16777216);
        unsigned short* F  = (unsigned short*)(ws + 16777216 + 524288);
        float* rsum        = (float*)(ws + 16777216 + 524288 + 16777216);
        float* invr        = (float*)(ws + 16777216 + 524288 + 16777216 + 65536);

        prep_kernel<<<8192, 256, 0, stream>>>(ctx, W, Xb, Wb, rsum);
        gemm1_relu_fb<<<dim3(4, 128), 256, 0, stream>>>(Xb, Wb, F);
        gemm2_rsum<<<dim3(136, 8), 256, 0, stream>>>(F, rsum);
        invr_kernel<<<64, 256, 0, stream>>>(rsum, mask, invr);
        gemm2_write_sym<<<dim3(136, 8), 256, 0, stream>>>(F, invr, mask, out);
    }
}

// Round 9
// 227.400 us; speedup vs baseline: 1.9066x; 1.9066x over previous
//
#include <hip/hip_runtime.h>

// Problem constants
#define Bc 8
#define Nc 2048
#define Dc 512
#define PH 512            // P*H
#define NN 4194304        // N*N
#define NT 136            // upper-tri 128x128 tiles: 16*17/2

#define BM 128
#define BN 128
#define BK 32

typedef __attribute__((ext_vector_type(8))) short bf16x8;
typedef __attribute__((ext_vector_type(4))) float f32x4;

static __device__ __forceinline__ unsigned short f2b(float x) {
    union { float f; unsigned u; } v; v.f = x;
    unsigned r = v.u + 0x7fffu + ((v.u >> 16) & 1u);   // RNE to bf16
    return (unsigned short)(r >> 16);
}

static __device__ __forceinline__ float b2f(unsigned short x) {
    return __builtin_bit_cast(float, (unsigned)x << 16);
}

// packed f32x2 -> bf16x2 (RNE), gfx950 instruction; low half = first operand
static __device__ __forceinline__ unsigned pk2(float lo, float hi) {
    unsigned r;
    asm("v_cvt_pk_bf16_f32 %0, %1, %2" : "=v"(r) : "v"(lo), "v"(hi));
    return r;
}

// async global->LDS DMA, 16 bytes per lane; LDS dest = wave-uniform base + lane*16
static __device__ __forceinline__ void load16_lds(const unsigned short* g, unsigned short* l) {
    __builtin_amdgcn_global_load_lds(
        (const __attribute__((address_space(1))) void*)g,
        (__attribute__((address_space(3))) void*)l,
        16, 0, 0);
}

// ---------------------------------------------------------------------------
// GEMM1 (fused conversion + rsum zero): F = relu(bf16(ctx) @ bf16(W)^T) from
// fp32 inputs. Verbatim R6 core; additionally each of the 512 blocks zeroes a
// 128-B slice of rsum (512*32*4B = 65536B exactly) -> memset node removed.
// grid: 512 1-D, XCD swizzle: 4 col-blocks of one A-row-panel on ONE XCD.
// ---------------------------------------------------------------------------
__global__ __launch_bounds__(256) void gemm1_fused(
    const float* __restrict__ ctx, const float* __restrict__ W,
    unsigned short* __restrict__ F, float* __restrict__ rsum) {
    __shared__ unsigned short As[BM * BK];
    __shared__ unsigned short Bs[BN * BK];
    const int tid = threadIdx.x;
    const int lane = tid & 63;
    const int wave = tid >> 6;
    const int wm = wave >> 1, wn = wave & 1;
    const int bid = blockIdx.x;
    const int row0 = ((bid & 7) + ((bid >> 5) << 3)) * BM;   // y = (bid&7)+8*(bid>>5)
    const int col0 = ((bid >> 3) & 3) * BN;                  // c = (bid>>3)&3

    if (tid < 32) rsum[bid * 32 + tid] = 0.0f;               // 512 blocks cover 16384 floats

    f32x4 acc[4][4] = {};

    for (int k0 = 0; k0 < Dc; k0 += BK) {
        int4 aw[2], bw[2];
#pragma unroll
        for (int j = 0; j < 2; ++j) {
            int e = j * 256 + tid;
            int rr = e >> 2, cc = e & 3;
            const float4* ga = (const float4*)&ctx[(size_t)(row0 + rr) * Dc + k0 + cc * 8];
            const float4* gb = (const float4*)&W[(size_t)(col0 + rr) * Dc + k0 + cc * 8];
            float4 a0 = ga[0], a1 = ga[1];
            float4 b0 = gb[0], b1 = gb[1];
            aw[j].x = pk2(a0.x, a0.y); aw[j].y = pk2(a0.z, a0.w);
            aw[j].z = pk2(a1.x, a1.y); aw[j].w = pk2(a1.z, a1.w);
            bw[j].x = pk2(b0.x, b0.y); bw[j].y = pk2(b0.z, b0.w);
            bw[j].z = pk2(b1.x, b1.y); bw[j].w = pk2(b1.z, b1.w);
        }
#pragma unroll
        for (int j = 0; j < 2; ++j) {
            int e = j * 256 + tid;
            *(int4*)&As[e * 8] = aw[j];
            *(int4*)&Bs[e * 8] = bw[j];
        }
        __syncthreads();

        bf16x8 af[4], bfr[4];
#pragma unroll
        for (int i = 0; i < 4; ++i) {
            af[i]  = *(const bf16x8*)&As[(wm * 64 + i * 16 + (lane & 15)) * BK + (lane >> 4) * 8];
            bfr[i] = *(const bf16x8*)&Bs[(wn * 64 + i * 16 + (lane & 15)) * BK + (lane >> 4) * 8];
        }
#pragma unroll
        for (int mi = 0; mi < 4; ++mi)
#pragma unroll
            for (int ni = 0; ni < 4; ++ni)
                acc[mi][ni] = __builtin_amdgcn_mfma_f32_16x16x32_bf16(af[mi], bfr[ni], acc[mi][ni], 0, 0, 0);
        __syncthreads();
    }

#pragma unroll
    for (int mi = 0; mi < 4; ++mi) {
#pragma unroll
        for (int ni = 0; ni < 4; ++ni) {
            int col  = col0 + wn * 64 + ni * 16 + (lane & 15);
            int rowb = row0 + wm * 64 + mi * 16 + ((lane >> 4) << 2);
#pragma unroll
            for (int r = 0; r < 4; ++r) {
                float v = fmaxf(acc[mi][ni][r], 0.0f);
                F[(size_t)(rowb + r) * PH + col] = f2b(v);
            }
        }
    }
}

// ---------------------------------------------------------------------------
// pass 2: tri-GEMM (BK=32, verified), e = exp(S/16-32) stored BF16 (full fp32
// exponent range), rsum (fp32) atomics. Diag tiles (i==j) stage only A (B==A).
// grid: 1088 1-D (b = blk&7 -> batch==XCD affinity), block 256.  (R6 verbatim)
// ---------------------------------------------------------------------------
__global__ __launch_bounds__(256) void gemm2_store(
    const unsigned short* __restrict__ F, float* __restrict__ rsum,
    unsigned short* __restrict__ Ework) {
    __shared__ unsigned short As[BM * BK];
    __shared__ unsigned short Bs[BN * BK];
    const int tid = threadIdx.x;
    const int lane = tid & 63;
    const int wave = tid >> 6;
    const int wm = wave >> 1, wn = wave & 1;
    const int l15 = lane & 15, q = lane >> 4;
    const int b = blockIdx.x & 7;          // batch -> XCD (L2 locality heuristic)
    const int idx = blockIdx.x >> 3;

    // upper-triangular tile index: idx = j*(j+1)/2 + i, i <= j
    int j = 0;
    while (((j + 1) * (j + 2) / 2) <= idx) ++j;
    int i = idx - j * (j + 1) / 2;
    const int row0 = i * BM;
    const int col0 = j * BN;
    const bool offd = (i != j);
    const unsigned short* Fb = F + (size_t)b * Nc * PH;

    f32x4 acc[4][4] = {};

    for (int k0 = 0; k0 < PH; k0 += BK) {
#pragma unroll
        for (int jj = 0; jj < 2; ++jj) {
            int e = jj * 256 + tid;
            int rr = e >> 2, cc = e & 3;
            load16_lds(&Fb[(size_t)(row0 + rr) * PH + k0 + cc * 8], &As[e * 8]);
            if (offd)
                load16_lds(&Fb[(size_t)(col0 + rr) * PH + k0 + cc * 8], &Bs[e * 8]);
        }
        __syncthreads();

        bf16x8 af[4], bfr[4];
#pragma unroll
        for (int qq = 0; qq < 4; ++qq)
            af[qq] = *(const bf16x8*)&As[(wm * 64 + qq * 16 + l15) * BK + q * 8];
        if (offd) {
#pragma unroll
            for (int qq = 0; qq < 4; ++qq)
                bfr[qq] = *(const bf16x8*)&Bs[(wn * 64 + qq * 16 + l15) * BK + q * 8];
        } else {
#pragma unroll
            for (int qq = 0; qq < 4; ++qq)
                bfr[qq] = *(const bf16x8*)&As[(wn * 64 + qq * 16 + l15) * BK + q * 8];
        }
#pragma unroll
        for (int mi = 0; mi < 4; ++mi)
#pragma unroll
            for (int ni = 0; ni < 4; ++ni)
                acc[mi][ni] = __builtin_amdgcn_mfma_f32_16x16x32_bf16(af[mi], bfr[ni], acc[mi][ni], 0, 0, 0);
        __syncthreads();
    }

    // epilogue: e = exp(S/16-32); store tile bf16; accumulate fp32 sums
    unsigned short* Et = Ework + (size_t)(b * NT + idx) * 16384;

    float csum[4] = {0.f, 0.f, 0.f, 0.f};
    float rsm[4][4];
#pragma unroll
    for (int mi = 0; mi < 4; ++mi)
#pragma unroll
        for (int r = 0; r < 4; ++r) rsm[mi][r] = 0.f;

#pragma unroll
    for (int mi = 0; mi < 4; ++mi) {
#pragma unroll
        for (int ni = 0; ni < 4; ++ni) {
#pragma unroll
            for (int r = 0; r < 4; ++r) {
                float e = __expf(acc[mi][ni][r] * 0.0625f - 32.0f);
                Et[(wm * 64 + mi * 16 + (q << 2) + r) * 128 + wn * 64 + ni * 16 + l15] = f2b(e);
                csum[ni] += e;
                rsm[mi][r] += e;
            }
        }
    }
#pragma unroll
    for (int ni = 0; ni < 4; ++ni) {
        float s = csum[ni];
        s += __shfl_xor(s, 16);
        s += __shfl_xor(s, 32);
        if ((lane >> 4) == 0)
            atomicAdd(&rsum[b * Nc + col0 + wn * 64 + ni * 16 + lane], s);
    }
    if (offd) {
#pragma unroll
        for (int mi = 0; mi < 4; ++mi) {
#pragma unroll
            for (int r = 0; r < 4; ++r) {
                float s = rsm[mi][r];
                s += __shfl_xor(s, 1);
                s += __shfl_xor(s, 2);
                s += __shfl_xor(s, 4);
                s += __shfl_xor(s, 8);
                if ((lane & 15) == 0)
                    atomicAdd(&rsum[b * Nc + row0 + wm * 64 + mi * 16 + ((lane >> 4) << 2) + r], s);
            }
        }
    }
}

// ---------------------------------------------------------------------------
// pass 3 (final): pure memory-bound scatter, bf16 e-tiles, inline invr.
// grid 1088, block 256.  (R5/R6 verbatim)
// ---------------------------------------------------------------------------
__global__ __launch_bounds__(256) void scatter_out(
    const unsigned short* __restrict__ Ework, const float* __restrict__ rsum,
    const int* __restrict__ mask, float* __restrict__ out) {
    __shared__ float Ts[32 * 132];
    __shared__ float invA[128];   // invr for cols col0..col0+127 (m-axis)
    __shared__ float invB[128];   // invr for rows row0..row0+127 (mirror m-axis)
    const int tid = threadIdx.x;
    const int b = blockIdx.x & 7;
    const int idx = blockIdx.x >> 3;

    int j = 0;
    while (((j + 1) * (j + 2) / 2) <= idx) ++j;
    int i = idx - j * (j + 1) / 2;
    const int row0 = i * BM;   // n-range of stored tile rows
    const int col0 = j * BN;   // m-range of stored tile cols

    const unsigned short* Et = Ework + (size_t)(b * NT + idx) * 16384;
    const float* rsb  = rsum + b * Nc;
    const int*   mb   = mask + b * Nc;
    float* outb = out + (size_t)b * NN;

    // inline invr (one value per thread)
    if (tid < 128)       invA[tid]       = (float)mb[col0 + tid]       / rsb[col0 + tid];
    else                 invB[tid - 128] = (float)mb[row0 + tid - 128] / rsb[row0 + tid - 128];
    __syncthreads();

    const int cl = tid >> 3, f0 = tid & 7;   // phase A: 32 rows x 8 lanes/row
    const int mc = tid >> 1, h  = tid & 1;   // phase B: 128 mirror-rows x 2 halves

    for (int ci = 0; ci < 4; ++ci) {         // 32-row chunks of the 128x128 tile
        if (ci) __syncthreads();             // Ts reuse across chunks
        const int r = ci * 32 + cl;
        const int n = row0 + r;
        const float mrow = (float)mb[n];
#pragma unroll
        for (int g = 0; g < 2; ++g) {        // 2 x 8 bf16 (16B load) per lane
            const int c0 = 64 * g + 8 * f0;
            union { int4 iv; unsigned short hv[8]; } u;
            u.iv = *(const int4*)&Et[r * 128 + c0];
            float ev[8];
#pragma unroll
            for (int k = 0; k < 8; ++k) ev[k] = b2f(u.hv[k]);
            *(float4*)&Ts[cl * 132 + c0]     = *(float4*)&ev[0];
            *(float4*)&Ts[cl * 132 + c0 + 4] = *(float4*)&ev[4];
            float4 iv0 = *(const float4*)&invA[c0];
            float4 iv1 = *(const float4*)&invA[c0 + 4];
            float4 o0, o1;
            o0.x = ev[0] * iv0.x * mrow;
            o0.y = ev[1] * iv0.y * mrow;
            o0.z = ev[2] * iv0.z * mrow;
            o0.w = ev[3] * iv0.w * mrow;
            o1.x = ev[4] * iv1.x * mrow;
            o1.y = ev[5] * iv1.y * mrow;
            o1.z = ev[6] * iv1.z * mrow;
            o1.w = ev[7] * iv1.w * mrow;
            *(float4*)&outb[(size_t)n * Nc + col0 + c0]     = o0;
            *(float4*)&outb[(size_t)n * Nc + col0 + c0 + 4] = o1;
        }
        if (i == j) continue;                // diag tile: no mirror (uniform branch)
        __syncthreads();
        const int a = col0 + mc;             // mirror out-row
        const float mcol = (float)mb[a];
        const int lb0 = ci * 32 + 16 * h;    // offset within invB / Ts rows
        const int nb0 = row0 + lb0;
#pragma unroll
        for (int u = 0; u < 4; ++u) {
            float4 iv = *(const float4*)&invB[lb0 + 4 * u];
            float4 o;
            o.x = Ts[(16 * h + 4 * u + 0) * 132 + mc] * iv.x * mcol;
            o.y = Ts[(16 * h + 4 * u + 1) * 132 + mc] * iv.y * mcol;
            o.z = Ts[(16 * h + 4 * u + 2) * 132 + mc] * iv.z * mcol;
            o.w = Ts[(16 * h + 4 * u + 3) * 132 + mc] * iv.w * mcol;
            *(float4*)&outb[(size_t)a * Nc + nb0 + 4 * u] = o;
        }
    }
}

// ---------------------------------------------------------------------------
// FALLBACK (small workspace): original recompute path, verbatim.
// ---------------------------------------------------------------------------
__global__ __launch_bounds__(256) void prep_kernel(
    const float* __restrict__ ctx, const float* __restrict__ W,
    unsigned short* __restrict__ Xb, unsigned short* __restrict__ Wb,
    float* __restrict__ rsum) {
    int t = blockIdx.x * 256 + threadIdx.x;
    if (t < 2097152) {
        float4 v = ((const float4*)ctx)[t];
        ushort4 o;
        o.x = f2b(v.x); o.y = f2b(v.y); o.z = f2b(v.z); o.w = f2b(v.w);
        ((ushort4*)Xb)[t] = o;
    }
    if (t < 65536) {
        float4 v = ((const float4*)W)[t];
        ushort4 o;
        o.x = f2b(v.x); o.y = f2b(v.y); o.z = f2b(v.z); o.w = f2b(v.w);
        ((ushort4*)Wb)[t] = o;
    }
    if (t < 4096) {
        float4 z; z.x = 0.f; z.y = 0.f; z.z = 0.f; z.w = 0.f;
        ((float4*)rsum)[t] = z;
    }
}

__global__ __launch_bounds__(256) void invr_kernel(
    const float* __restrict__ rsum, const int* __restrict__ mask,
    float* __restrict__ invr) {
    int t = blockIdx.x * 256 + threadIdx.x;
    if (t < Bc * Nc) invr[t] = (float)mask[t] / rsum[t];
}

__global__ __launch_bounds__(256) void gemm1_relu_fb(
    const unsigned short* __restrict__ Xb, const unsigned short* __restrict__ Wb,
    unsigned short* __restrict__ F) {
    __shared__ unsigned short As[BM * BK];
    __shared__ unsigned short Bs[BN * BK];
    const int tid = threadIdx.x;
    const int lane = tid & 63;
    const int wave = tid >> 6;
    const int wm = wave >> 1, wn = wave & 1;
    const int row0 = blockIdx.y * BM;
    const int col0 = blockIdx.x * BN;

    f32x4 acc[4][4] = {};

    for (int k0 = 0; k0 < Dc; k0 += BK) {
#pragma unroll
        for (int j = 0; j < 2; ++j) {
            int e = j * 256 + tid;
            int rr = e >> 2, cc = e & 3;
            load16_lds(&Xb[(size_t)(row0 + rr) * Dc + k0 + cc * 8], &As[e * 8]);
            load16_lds(&Wb[(size_t)(col0 + rr) * Dc + k0 + cc * 8], &Bs[e * 8]);
        }
        __syncthreads();

        bf16x8 af[4], bfr[4];
#pragma unroll
        for (int i = 0; i < 4; ++i) {
            af[i]  = *(const bf16x8*)&As[(wm * 64 + i * 16 + (lane & 15)) * BK + (lane >> 4) * 8];
            bfr[i] = *(const bf16x8*)&Bs[(wn * 64 + i * 16 + (lane & 15)) * BK + (lane >> 4) * 8];
        }
#pragma unroll
        for (int mi = 0; mi < 4; ++mi)
#pragma unroll
            for (int ni = 0; ni < 4; ++ni)
                acc[mi][ni] = __builtin_amdgcn_mfma_f32_16x16x32_bf16(af[mi], bfr[ni], acc[mi][ni], 0, 0, 0);
        __syncthreads();
    }

#pragma unroll
    for (int mi = 0; mi < 4; ++mi) {
#pragma unroll
        for (int ni = 0; ni < 4; ++ni) {
            int col  = col0 + wn * 64 + ni * 16 + (lane & 15);
            int rowb = row0 + wm * 64 + mi * 16 + ((lane >> 4) << 2);
#pragma unroll
            for (int r = 0; r < 4; ++r) {
                float v = fmaxf(acc[mi][ni][r], 0.0f);
                F[(size_t)(rowb + r) * PH + col] = f2b(v);
            }
        }
    }
}

__global__ __launch_bounds__(256) void gemm2_rsum(
    const unsigned short* __restrict__ F, float* __restrict__ rsum) {
    __shared__ unsigned short As[BM * BK];
    __shared__ unsigned short Bs[BN * BK];
    const int tid = threadIdx.x;
    const int lane = tid & 63;
    const int wave = tid >> 6;
    const int wm = wave >> 1, wn = wave & 1;
    const int b = blockIdx.y;

    int idx = blockIdx.x;
    int j = 0;
    while (((j + 1) * (j + 2) / 2) <= idx) ++j;
    int i = idx - j * (j + 1) / 2;
    const int row0 = i * BM;
    const int col0 = j * BN;
    const unsigned short* Fb = F + (size_t)b * Nc * PH;

    f32x4 acc[4][4] = {};

    for (int k0 = 0; k0 < PH; k0 += BK) {
#pragma unroll
        for (int jj = 0; jj < 2; ++jj) {
            int e = jj * 256 + tid;
            int rr = e >> 2, cc = e & 3;
            load16_lds(&Fb[(size_t)(row0 + rr) * PH + k0 + cc * 8], &As[e * 8]);
            load16_lds(&Fb[(size_t)(col0 + rr) * PH + k0 + cc * 8], &Bs[e * 8]);
        }
        __syncthreads();

        bf16x8 af[4], bfr[4];
#pragma unroll
        for (int q = 0; q < 4; ++q) {
            af[q]  = *(const bf16x8*)&As[(wm * 64 + q * 16 + (lane & 15)) * BK + (lane >> 4) * 8];
            bfr[q] = *(const bf16x8*)&Bs[(wn * 64 + q * 16 + (lane & 15)) * BK + (lane >> 4) * 8];
        }
#pragma unroll
        for (int mi = 0; mi < 4; ++mi)
#pragma unroll
            for (int ni = 0; ni < 4; ++ni)
                acc[mi][ni] = __builtin_amdgcn_mfma_f32_16x16x32_bf16(af[mi], bfr[ni], acc[mi][ni], 0, 0, 0);
        __syncthreads();
    }

    float csum[4] = {0.f, 0.f, 0.f, 0.f};
    float rsm[4][4];
#pragma unroll
    for (int mi = 0; mi < 4; ++mi)
#pragma unroll
        for (int r = 0; r < 4; ++r) rsm[mi][r] = 0.f;

#pragma unroll
    for (int mi = 0; mi < 4; ++mi) {
#pragma unroll
        for (int ni = 0; ni < 4; ++ni) {
#pragma unroll
            for (int r = 0; r < 4; ++r) {
                float e = __expf(acc[mi][ni][r] * 0.0625f - 32.0f);
                csum[ni] += e;
                rsm[mi][r] += e;
            }
        }
    }
#pragma unroll
    for (int ni = 0; ni < 4; ++ni) {
        float s = csum[ni];
        s += __shfl_xor(s, 16);
        s += __shfl_xor(s, 32);
        if ((lane >> 4) == 0)
            atomicAdd(&rsum[b * Nc + col0 + wn * 64 + ni * 16 + lane], s);
    }
    if (i != j) {
#pragma unroll
        for (int mi = 0; mi < 4; ++mi) {
#pragma unroll
            for (int r = 0; r < 4; ++r) {
                float s = rsm[mi][r];
                s += __shfl_xor(s, 1);
                s += __shfl_xor(s, 2);
                s += __shfl_xor(s, 4);
                s += __shfl_xor(s, 8);
                if ((lane & 15) == 0)
                    atomicAdd(&rsum[b * Nc + row0 + wm * 64 + mi * 16 + ((lane >> 4) << 2) + r], s);
            }
        }
    }
}

__global__ __launch_bounds__(256) void gemm2_write_sym(
    const unsigned short* __restrict__ F, const float* __restrict__ invr,
    const int* __restrict__ mask, float* __restrict__ out) {
    __shared__ unsigned short As[BM * BK];
    __shared__ unsigned short Bs[BN * BK];
    __shared__ float Ts[32 * 132];
    const int tid = threadIdx.x;
    const int lane = tid & 63;
    const int wave = tid >> 6;
    const int wm = wave >> 1, wn = wave & 1;
    const int l15 = lane & 15, q = lane >> 4;
    const int b = blockIdx.y;

    int idx = blockIdx.x;
    int j = 0;
    while (((j + 1) * (j + 2) / 2) <= idx) ++j;
    int i = idx - j * (j + 1) / 2;
    const int row0 = i * BM;
    const int col0 = j * BN;
    const unsigned short* Fb = F + (size_t)b * Nc * PH;

    f32x4 acc[4][4] = {};

    for (int k0 = 0; k0 < PH; k0 += BK) {
#pragma unroll
        for (int jj = 0; jj < 2; ++jj) {
            int e = jj * 256 + tid;
            int rr = e >> 2, cc = e & 3;
            load16_lds(&Fb[(size_t)(row0 + rr) * PH + k0 + cc * 8], &As[e * 8]);
            load16_lds(&Fb[(size_t)(col0 + rr) * PH + k0 + cc * 8], &Bs[e * 8]);
        }
        __syncthreads();

        bf16x8 af[4], bfr[4];
#pragma unroll
        for (int qq = 0; qq < 4; ++qq) {
            af[qq]  = *(const bf16x8*)&As[(wm * 64 + qq * 16 + l15) * BK + q * 8];
            bfr[qq] = *(const bf16x8*)&Bs[(wn * 64 + qq * 16 + l15) * BK + q * 8];
        }
#pragma unroll
        for (int mi = 0; mi < 4; ++mi)
#pragma unroll
            for (int ni = 0; ni < 4; ++ni)
                acc[mi][ni] = __builtin_amdgcn_mfma_f32_16x16x32_bf16(af[mi], bfr[ni], acc[mi][ni], 0, 0, 0);
        __syncthreads();
    }

#pragma unroll
    for (int mi = 0; mi < 4; ++mi)
#pragma unroll
        for (int ni = 0; ni < 4; ++ni)
#pragma unroll
            for (int r = 0; r < 4; ++r)
                acc[mi][ni][r] = __expf(acc[mi][ni][r] * 0.0625f - 32.0f);

    float* outb = out + (size_t)b * NN;

    float iv[4];
#pragma unroll
    for (int ni = 0; ni < 4; ++ni)
        iv[ni] = invr[b * Nc + col0 + wn * 64 + ni * 16 + l15];
#pragma unroll
    for (int mi = 0; mi < 4; ++mi) {
        int rowb = row0 + wm * 64 + mi * 16 + (q << 2);
        const int4 mr4 = *(const int4*)&mask[b * Nc + rowb];
        float mr[4] = {(float)mr4.x, (float)mr4.y, (float)mr4.z, (float)mr4.w};
#pragma unroll
        for (int ni = 0; ni < 4; ++ni) {
            int col = col0 + wn * 64 + ni * 16 + l15;
#pragma unroll
            for (int r = 0; r < 4; ++r)
                outb[(size_t)(rowb + r) * Nc + col] = acc[mi][ni][r] * iv[ni] * mr[r];
        }
    }

    if (i != j) {
#pragma unroll
        for (int ci = 0; ci < 4; ++ci) {
            __syncthreads();
            if (wn == (ci >> 1)) {
#pragma unroll
                for (int ni2 = 0; ni2 < 2; ++ni2) {
                    int ni = (ci & 1) * 2 + ni2;
#pragma unroll
                    for (int mi = 0; mi < 4; ++mi) {
                        *(float4*)&Ts[(ni2 * 16 + l15) * 132 + wm * 64 + mi * 16 + (q << 2)] =
                            *(float4*)&acc[mi][ni];
                    }
                }
            }
            __syncthreads();
            int cl = tid >> 3;
            int f0 = tid & 7;
            int nn = col0 + ci * 32 + cl;
            float mrow = (float)mask[b * Nc + nn];
            float* orow = &outb[(size_t)nn * Nc + row0];
#pragma unroll
            for (int g = 0; g < 4; ++g) {
                int f = f0 + g * 8;
                float4 ev  = *(float4*)&Ts[cl * 132 + 4 * f];
                float4 iv4 = *(const float4*)&invr[b * Nc + row0 + 4 * f];
                float4 o;
                o.x = ev.x * iv4.x * mrow;
                o.y = ev.y * iv4.y * mrow;
                o.z = ev.z * iv4.z * mrow;
                o.w = ev.w * iv4.w * mrow;
                *(float4*)&orow[4 * f] = o;
            }
        }
    }
}

// ---------------------------------------------------------------------------
extern "C" void kernel_launch(void* const* d_in, const int* in_sizes, int n_in,
                              void* d_out, int out_size, void* d_ws, size_t ws_size,
                              hipStream_t stream) {
    const float* ctx  = (const float*)d_in[0];   // [8,2048,512] fp32
    const float* W    = (const float*)d_in[1];   // [16,32,512] fp32
    const int*   mask = (const int*)d_in[2];     // [8,2048] int32
    float* out = (float*)d_out;                  // [8,2048,2048] fp32

    char* ws = (char*)d_ws;

    // Layout (bf16 Ework): 1088 tiles * 32KB = 35651584 B.
    //   [0 .. 35651584)           Ework bf16
    //   [35651584 .. 52428800)    F (bf16, 16384x512)
    //   [52428800 .. 52494336)    rsum (zeroed inside gemm1_fused)
    const size_t NEED = 52494336;

    if (ws_size >= NEED) {
        unsigned short* Ework = (unsigned short*)ws;
        unsigned short* F     = (unsigned short*)(ws + 35651584);
        float*          rsum  = (float*)(ws + 52428800);

        gemm1_fused<<<512, 256, 0, stream>>>(ctx, W, F, rsum);
        gemm2_store<<<1088, 256, 0, stream>>>(F, rsum, Ework);      // tri-GEMM + bf16 e-store + rsum
        scatter_out<<<1088, 256, 0, stream>>>(Ework, rsum, mask, out);  // inline invr + pure-BW pass
    } else {
        // fallback: original recompute path (needs ~34.2 MB)
        unsigned short* Xb = (unsigned short*)ws;
        unsigned short* Wb = (unsigned short*)(ws + 16777216);
        unsigned short* F  = (unsigned short*)(ws + 16777216 + 524288);
        float* rsum        = (float*)(ws + 16777216 + 524288 + 16777216);
        float* invr        = (float*)(ws + 16777216 + 524288 + 16777216 + 65536);

        prep_kernel<<<8192, 256, 0, stream>>>(ctx, W, Xb, Wb, rsum);
        gemm1_relu_fb<<<dim3(4, 128), 256, 0, stream>>>(Xb, Wb, F);
        gemm2_rsum<<<dim3(136, 8), 256, 0, stream>>>(F, rsum);
        invr_kernel<<<64, 256, 0, stream>>>(rsum, mask, invr);
        gemm2_write_sym<<<dim3(136, 8), 256, 0, stream>>>(F, invr, mask, out);
    }
}